// Round 6
// baseline (101.701 us; speedup 1.0000x reference)
//
#include <hip/hip_runtime.h>
#include <hip/hip_fp16.h>

// Problem constants: L=4, DIM=17, S=4, B=4, H=256, W=256, BINSIZE=16
#define HH   256
#define WW   256
#define HWPX (HH * WW)           // 65536
#define DD   17
#define D4   (17 * 17 * 17 * 17) // 83521
#define NL   4
#define SS   16                  // S*S
#define LUT_FLOATS  (NL * D4 * SS)            // 5,345,344 floats
#define LUT_BYTES_H ((size_t)LUT_FLOATS * 2)  // ~10.7 MB (fp16 transposed copy)

// ---------------------------------------------------------------------------
// Kernel 1: transpose + fp16-convert LUT (L, D4, 16) f32 -> (D4, L, 16) f16.
// One vertex's four l-rows become exactly ONE 128B cache line.
// ---------------------------------------------------------------------------
__global__ __launch_bounds__(256) void lut_transpose_h_kernel(
    const float4* __restrict__ src,   // (L, D4, 4) float4
    ushort* __restrict__ dst)         // (D4, L, 16) halfs as ushort
{
    int t = blockIdx.x * blockDim.x + threadIdx.x;  // 4-half chunk index in dst
    if (t >= D4 * NL * 4) return;
    int c4 = t & 3;
    int l  = (t >> 2) & 3;
    int v  = t >> 4;
    float4 r = src[(size_t)l * (D4 * 4) + (size_t)v * 4 + c4];
    ushort4 h;
    h.x = __half_as_ushort(__float2half_rn(r.x));
    h.y = __half_as_ushort(__float2half_rn(r.y));
    h.z = __half_as_ushort(__float2half_rn(r.z));
    h.w = __half_as_ushort(__float2half_rn(r.w));
    *((ushort4*)(dst + (size_t)t * 4)) = h;   // coalesced 8B stores
}

// ---------------------------------------------------------------------------
// Kernel 2: main interpolation. 16 lanes per pixel; lane j loads the 8B
// chunk at byte offset 8*j of each vertex's 128B line (l = j>>2, channel
// quad q = j&3). One wave-load touches only 4 distinct lines (4 pixels x 1
// vertex) -> minimal 1.31M line transactions. Reduce over l with a 2-step
// shfl_xor butterfly (masks 4, 8); lanes j<4 store coalesced float4 rows.
// ---------------------------------------------------------------------------
__global__ __launch_bounds__(256) void lut4d_kernel_c16(
    const ushort* __restrict__ lutT,   // (D4, L, 16) fp16
    const float* __restrict__ weight,  // (B, L, H, W)
    const float* __restrict__ x,       // (B, 1, H, W)
    float* __restrict__ out)           // (B, 1, H*4, W*4)
{
    int tid = blockIdx.x * blockDim.x + threadIdx.x;  // [0, 16*B*H*W)
    int j     = tid & 15;     // lane role within pixel
    int l_idx = j >> 2;       // LUT layer this lane reduces
    int q     = j & 3;        // channel quad (= output tile row)
    int p = tid >> 4;         // pixel id
    int b  = p >> 16;
    int hw = p & 65535;
    int h  = hw >> 8;
    int w  = hw & 255;

    const float* xb = x + b * HWPX;
    int h1 = (h + 1 < HH) ? (h + 1) : (HH - 2);   // reflect pad
    int w1 = (w + 1 < WW) ? (w + 1) : (WW - 2);

    float pix0 = xb[h  * WW + w ];
    float pix1 = xb[h  * WW + w1];
    float pix2 = xb[h1 * WW + w ];
    float pix3 = xb[h1 * WW + w1];

    const float inv = 1.0f / 16.0f;
    float t0 = pix0 * inv, t1 = pix1 * inv, t2 = pix2 * inv, t3 = pix3 * inv;
    float bf0 = floorf(t0), bf1 = floorf(t1), bf2 = floorf(t2), bf3 = floorf(t3);
    float f0 = t0 - bf0, f1 = t1 - bf1, f2 = t2 - bf2, f3 = t3 - bf3;

    int b0 = min(max((int)bf0, 0), DD - 2);
    int b1 = min(max((int)bf1, 0), DD - 2);
    int b2 = min(max((int)bf2, 0), DD - 2);
    int b3 = min(max((int)bf3, 0), DD - 2);

    // Stable descending sort of (frac, stride); strides strictly decrease
    // with original index so tie-break by larger stride == stable argsort.
    float s0f = f0, s1f = f1, s2f = f2, s3f = f3;
    int   s0s = 4913, s1s = 289, s2s = 17, s3s = 1;

#define CSWAP(fa, sa, fb, sb)                                          \
    do {                                                               \
        bool sw = (fb > fa) || ((fb == fa) && (sb > sa));              \
        float tf = fa; int ts = sa;                                    \
        if (sw) { fa = fb; sa = sb; fb = tf; sb = ts; }                \
    } while (0)

    CSWAP(s0f, s0s, s1f, s1s);
    CSWAP(s2f, s2s, s3f, s3s);
    CSWAP(s0f, s0s, s2f, s2s);
    CSWAP(s1f, s1s, s3f, s3s);
    CSWAP(s1f, s1s, s2f, s2s);
#undef CSWAP

    float wts[5];
    wts[0] = 1.0f - s0f;
    wts[1] = s0f - s1f;
    wts[2] = s1f - s2f;
    wts[3] = s2f - s3f;
    wts[4] = s3f;

    int flats[5];
    flats[0] = ((b0 * DD + b1) * DD + b2) * DD + b3;
    flats[1] = flats[0] + s0s;
    flats[2] = flats[1] + s1s;
    flats[3] = flats[2] + s2s;
    flats[4] = flats[3] + s3s;

    // This lane's blend coefficient source: weight[b, l_idx, hw]
    float wl = weight[(size_t)b * (NL * HWPX) + (size_t)l_idx * HWPX + hw];

    // 5 independent 8B gathers: lane j covers bytes 8j..8j+7 of the vertex
    // line (halfs l_idx*16 + q*4 .. +3).
    uint2 r[5];
#pragma unroll
    for (int k = 0; k < 5; ++k) {
        const ushort* vbase = lutT + (size_t)flats[k] * (NL * SS);
        r[k] = *((const uint2*)(vbase + j * 4));
    }

    float a0 = 0.f, a1 = 0.f, a2 = 0.f, a3 = 0.f;
#pragma unroll
    for (int k = 0; k < 5; ++k) {
        float c = wl * wts[k];
        __half2 h01 = *reinterpret_cast<const __half2*>(&r[k].x);
        __half2 h23 = *reinterpret_cast<const __half2*>(&r[k].y);
        float2 f01 = __half22float2(h01);
        float2 f23 = __half22float2(h23);
        a0 = fmaf(c, f01.x, a0);
        a1 = fmaf(c, f01.y, a1);
        a2 = fmaf(c, f23.x, a2);
        a3 = fmaf(c, f23.y, a3);
    }

    // Butterfly-reduce over l (lane bits 2 and 3 within the 16-lane group).
    a0 += __shfl_xor(a0, 4);  a0 += __shfl_xor(a0, 8);
    a1 += __shfl_xor(a1, 4);  a1 += __shfl_xor(a1, 8);
    a2 += __shfl_xor(a2, 4);  a2 += __shfl_xor(a2, 8);
    a3 += __shfl_xor(a3, 4);  a3 += __shfl_xor(a3, 8);

    // Lanes with l_idx==0 store tile row q: out[b, 0, h*4+q, w*4 .. +3]
    if (l_idx == 0) {
        float* ob = out + (size_t)b * (HH * 4) * (WW * 4)
                        + (size_t)(h * 4 + q) * (WW * 4) + (w * 4);
        *((float4*)ob) = make_float4(a0, a1, a2, a3);
    }
}

// ---------------------------------------------------------------------------
// Fallback (no workspace): original layout, fp32.
// ---------------------------------------------------------------------------
__global__ __launch_bounds__(256) void lut4d_kernel_fallback(
    const float* __restrict__ lut,
    const float* __restrict__ weight,
    const float* __restrict__ x,
    float* __restrict__ out)
{
    int p = blockIdx.x * blockDim.x + threadIdx.x;
    int b  = p >> 16;
    int hw = p & 65535;
    int h  = hw >> 8;
    int w  = hw & 255;

    const float* xb = x + b * HWPX;
    int h1 = (h + 1 < HH) ? (h + 1) : (HH - 2);
    int w1 = (w + 1 < WW) ? (w + 1) : (WW - 2);

    float pix0 = xb[h  * WW + w ];
    float pix1 = xb[h  * WW + w1];
    float pix2 = xb[h1 * WW + w ];
    float pix3 = xb[h1 * WW + w1];

    const float inv = 1.0f / 16.0f;
    float t0 = pix0 * inv, t1 = pix1 * inv, t2 = pix2 * inv, t3 = pix3 * inv;
    float bf0 = floorf(t0), bf1 = floorf(t1), bf2 = floorf(t2), bf3 = floorf(t3);
    float f0 = t0 - bf0, f1 = t1 - bf1, f2 = t2 - bf2, f3 = t3 - bf3;

    int b0 = min(max((int)bf0, 0), DD - 2);
    int b1 = min(max((int)bf1, 0), DD - 2);
    int b2 = min(max((int)bf2, 0), DD - 2);
    int b3 = min(max((int)bf3, 0), DD - 2);

    float s0f = f0, s1f = f1, s2f = f2, s3f = f3;
    int   s0s = 4913, s1s = 289, s2s = 17, s3s = 1;

#define CSWAP(fa, sa, fb, sb)                                          \
    do {                                                               \
        bool sw = (fb > fa) || ((fb == fa) && (sb > sa));              \
        float tf = fa; int ts = sa;                                    \
        if (sw) { fa = fb; sa = sb; fb = tf; sb = ts; }                \
    } while (0)

    CSWAP(s0f, s0s, s1f, s1s);
    CSWAP(s2f, s2s, s3f, s3s);
    CSWAP(s0f, s0s, s2f, s2s);
    CSWAP(s1f, s1s, s3f, s3s);
    CSWAP(s1f, s1s, s2f, s2s);
#undef CSWAP

    float wts[5] = { 1.0f - s0f, s0f - s1f, s1f - s2f, s2f - s3f, s3f };
    int flats[5];
    flats[0] = ((b0 * DD + b1) * DD + b2) * DD + b3;
    flats[1] = flats[0] + s0s;
    flats[2] = flats[1] + s1s;
    flats[3] = flats[2] + s2s;
    flats[4] = flats[3] + s3s;

    float acc[SS];
#pragma unroll
    for (int i = 0; i < SS; ++i) acc[i] = 0.0f;

    const float* wb = weight + b * (NL * HWPX) + hw;

#pragma unroll
    for (int l = 0; l < NL; ++l) {
        float wlv = wb[l * HWPX];
        const float* lbase = lut + (size_t)l * D4 * SS;
#pragma unroll
        for (int k = 0; k < 5; ++k) {
            float c = wlv * wts[k];
            const float4* row = (const float4*)(lbase + (size_t)flats[k] * SS);
#pragma unroll
            for (int qq = 0; qq < 4; ++qq) {
                float4 rr = row[qq];
                acc[qq * 4 + 0] = fmaf(c, rr.x, acc[qq * 4 + 0]);
                acc[qq * 4 + 1] = fmaf(c, rr.y, acc[qq * 4 + 1]);
                acc[qq * 4 + 2] = fmaf(c, rr.z, acc[qq * 4 + 2]);
                acc[qq * 4 + 3] = fmaf(c, rr.w, acc[qq * 4 + 3]);
            }
        }
    }

    float* ob = out + (size_t)b * (HH * 4) * (WW * 4) + (size_t)(h * 4) * (WW * 4) + (w * 4);
#pragma unroll
    for (int i = 0; i < 4; ++i) {
        *((float4*)(ob + (size_t)i * (WW * 4))) =
            make_float4(acc[i * 4 + 0], acc[i * 4 + 1], acc[i * 4 + 2], acc[i * 4 + 3]);
    }
}

extern "C" void kernel_launch(void* const* d_in, const int* in_sizes, int n_in,
                              void* d_out, int out_size, void* d_ws, size_t ws_size,
                              hipStream_t stream) {
    const float* lut    = (const float*)d_in[0];
    // d_in[1] = tri_index (unused by the reference computation)
    const float* weight = (const float*)d_in[2];
    const float* x      = (const float*)d_in[3];
    float* out          = (float*)d_out;

    dim3 block(256);

    if (ws_size >= LUT_BYTES_H) {
        ushort* lutT = (ushort*)d_ws;
        int n_chunks = D4 * NL * 4;                   // 1,336,336 4-half chunks
        dim3 grid_t((n_chunks + 255) / 256);
        hipLaunchKernelGGL(lut_transpose_h_kernel, grid_t, block, 0, stream,
                           (const float4*)lut, lutT);
        dim3 grid_main(16384);  // 16 * 262144 threads / 256
        hipLaunchKernelGGL(lut4d_kernel_c16, grid_main, block, 0, stream,
                           lutT, weight, x, out);
    } else {
        dim3 grid_main(1024);
        hipLaunchKernelGGL(lut4d_kernel_fallback, grid_main, block, 0, stream,
                           lut, weight, x, out);
    }
}